// Round 1
// 470.960 us; speedup vs baseline: 1.0182x; 1.0182x over previous
//
#include <hip/hip_runtime.h>

#define T_DIM 4096
#define N_DIM 128
#define D_DIM 128
#define CHUNK 256
#define NCHUNK (T_DIM / CHUNK)   // 16
#define NEGE (-1.0e9f)
#define P_SKIP 1.0e-9f           // skipped mass <= 4096*1e-9 ~ 4e-6 << tol

// ---------------------------------------------------------------------------
// K1: energy[n,t] = dot(key[t,n,:], q[n,:]); masked t -> NEGE (key not read).
// Emits per-chunk max m_c and per-chunk expsum s_c = sum exp(e - m_c).
// Grid: N_DIM * NCHUNK blocks, 256 threads. (out-zeroing removed: finalize
// now writes out with plain stores, no atomics.)
// ---------------------------------------------------------------------------
__global__ __launch_bounds__(256) void energy_kernel(
    const float* __restrict__ q,        // (N,D)
    const float* __restrict__ key,      // (T,N,D)
    const int*   __restrict__ lens,     // (N)
    float*       __restrict__ att,      // (N,T) raw energies
    float*       __restrict__ blockmax, // (N,NCHUNK)
    float*       __restrict__ blocksum) // (N,NCHUNK)
{
    const int b    = blockIdx.x;
    const int n    = b & (N_DIM - 1);
    const int c    = b >> 7;            // b / N_DIM
    const int t0   = c * CHUNK;
    const int len  = lens[n];
    const int tid  = threadIdx.x;

    // Fast path: whole chunk masked -> vector-write NEGE, no key reads.
    if (t0 >= len) {
        if (tid < 64)
            ((float4*)(att + (size_t)n * T_DIM + t0))[tid] =
                make_float4(NEGE, NEGE, NEGE, NEGE);
        if (tid == 0) {
            blockmax[n * NCHUNK + c] = NEGE;
            blocksum[n * NCHUNK + c] = 0.0f;
        }
        return;
    }

    const int wave = tid >> 6;          // 0..3
    const int lane = tid & 63;
    const int half = lane >> 5;         // 0/1 (each half owns one t)
    const int l32  = lane & 31;

    // q fragment: float4 at d = l32*4 (covers all 128 d across 32 lanes)
    const float4 qv = *(const float4*)(q + n * D_DIM + l32 * 4);

    float evals[CHUNK / 8];             // 32 energies per lane (uniform per half)
    float lmax = NEGE;

    // Wave handles t pairs: t = t0 + wave*2 + i*8 + half, i in [0,32)
    #pragma unroll
    for (int i = 0; i < CHUNK / 8; ++i) {
        const int t = t0 + wave * 2 + i * 8 + half;
        float e;
        if (t < len) {   // uniform per 32-lane half
            const float4 kv = *(const float4*)(key + (size_t)t * (N_DIM * D_DIM)
                                               + n * D_DIM + l32 * 4);
            float p = kv.x * qv.x + kv.y * qv.y + kv.z * qv.z + kv.w * qv.w;
            p += __shfl_xor(p, 1);
            p += __shfl_xor(p, 2);
            p += __shfl_xor(p, 4);
            p += __shfl_xor(p, 8);
            p += __shfl_xor(p, 16);
            e = p;
        } else {
            e = NEGE;
        }
        if (l32 == 0) att[(size_t)n * T_DIM + t] = e;
        evals[i] = e;
        lmax = fmaxf(lmax, e);
    }

    // Block max (broadcast to all threads).
    lmax = fmaxf(lmax, __shfl_xor(lmax, 32));
    __shared__ float smax[4];
    __shared__ float ssum[4];
    if (lane == 0) smax[wave] = lmax;
    __syncthreads();
    const float m = fmaxf(fmaxf(smax[0], smax[1]), fmaxf(smax[2], smax[3]));

    // Per-chunk expsum. Lane-local sum already covers its half's 32 t's
    // (values uniform within half); add the other half, then across waves.
    float s = 0.f;
    #pragma unroll
    for (int i = 0; i < CHUNK / 8; ++i) s += __expf(evals[i] - m);
    s += __shfl_xor(s, 32);
    if (lane == 0) ssum[wave] = s;
    __syncthreads();
    if (tid == 0) {
        blockmax[n * NCHUNK + c] = m;
        blocksum[n * NCHUNK + c] = ssum[0] + ssum[1] + ssum[2] + ssum[3];
    }
}

// ---------------------------------------------------------------------------
// K2: per-n finalize. Rebuild global (m, Z) from 16 chunk stats; normalize
// the whole att row (raw -> p, masked tail -> exact 0 via exp underflow);
// stash p in LDS; compact the contributor set {t : p > P_SKIP} via LDS
// atomics; PV only over contributors (~1-3% of rows); block-reduce; plain
// store to out (no atomics, no pre-zero).
// Grid: N_DIM blocks, 256 threads.
// ---------------------------------------------------------------------------
__global__ __launch_bounds__(256) void finalize_kernel(
    float*       __restrict__ att,      // (N,T): raw in, normalized out
    const float* __restrict__ value,    // (T,N,D)
    const float* __restrict__ blockmax, // (N,NCHUNK)
    const float* __restrict__ blocksum, // (N,NCHUNK)
    float*       __restrict__ out)      // (N,D)
{
    const int n   = blockIdx.x;
    const int tid = threadIdx.x;

    __shared__ float sm[NCHUNK], ss[NCHUNK];
    __shared__ float sp[T_DIM];         // 16 KB: normalized p for whole row
    __shared__ int   slist[T_DIM];      // 16 KB: contributor t-indices
    __shared__ int   scount;

    if (tid < NCHUNK) {
        sm[tid] = blockmax[n * NCHUNK + tid];
        ss[tid] = blocksum[n * NCHUNK + tid];
    }
    if (tid == 0) scount = 0;
    __syncthreads();

    float m = sm[0];
    #pragma unroll
    for (int i = 1; i < NCHUNK; ++i) m = fmaxf(m, sm[i]);
    float Z = 0.f;
    #pragma unroll
    for (int i = 0; i < NCHUNK; ++i) Z += ss[i] * __expf(sm[i] - m);
    const float inv = 1.0f / Z;         // Z >= 1 (chunk holding global max)

    // Normalize full att row (float4), stash p in LDS.
    // Masked entries are NEGE -> __expf underflows to exact 0.0.
    float4* arow = (float4*)(att + (size_t)n * T_DIM);
    #pragma unroll
    for (int i = 0; i < T_DIM / 4 / 256; ++i) {   // 4 passes
        const int idx = i * 256 + tid;
        float4 e4 = arow[idx];
        float4 p4;
        p4.x = __expf(e4.x - m) * inv;
        p4.y = __expf(e4.y - m) * inv;
        p4.z = __expf(e4.z - m) * inv;
        p4.w = __expf(e4.w - m) * inv;
        arow[idx] = p4;
        ((float4*)sp)[idx] = p4;
    }
    __syncthreads();

    // Compact contributor list: t with p > P_SKIP (masked tail is exact 0,
    // auto-excluded). Worst case all 4096 -> degrades to dense loop.
    for (int t = tid; t < T_DIM; t += 256) {
        if (sp[t] > P_SKIP) {
            const int j = atomicAdd(&scount, 1);
            slist[j] = t;
        }
    }
    __syncthreads();

    // Sparse PV: threads = (d-quad qd:32, list-group g:8); coalesced 512 B
    // value loads per 32-lane group.
    const int nc = scount;
    const int qd = tid & 31;
    const int g  = tid >> 5;
    float4 acc = make_float4(0.f, 0.f, 0.f, 0.f);
    for (int j = g; j < nc; j += 8) {
        const int t = slist[j];
        const float a = sp[t];
        const float4 v = *(const float4*)(value + (size_t)t * (N_DIM * D_DIM)
                                          + n * D_DIM + qd * 4);
        acc.x += a * v.x;
        acc.y += a * v.y;
        acc.z += a * v.z;
        acc.w += a * v.w;
    }

    __shared__ float4 buf[256];
    buf[tid] = acc;
    __syncthreads();
    if (tid < 128) {
        float4 o = buf[tid + 128];
        buf[tid].x += o.x; buf[tid].y += o.y; buf[tid].z += o.z; buf[tid].w += o.w;
    }
    __syncthreads();
    if (tid < 64) {
        float4 o = buf[tid + 64];
        buf[tid].x += o.x; buf[tid].y += o.y; buf[tid].z += o.z; buf[tid].w += o.w;
    }
    __syncthreads();
    if (tid < 32) {
        float4 a0 = buf[tid];
        float4 a1 = buf[tid + 32];
        ((float4*)(out + n * D_DIM))[tid] =
            make_float4(a0.x + a1.x, a0.y + a1.y, a0.z + a1.z, a0.w + a1.w);
    }
}

extern "C" void kernel_launch(void* const* d_in, const int* in_sizes, int n_in,
                              void* d_out, int out_size, void* d_ws, size_t ws_size,
                              hipStream_t stream) {
    const float* q     = (const float*)d_in[0];   // (N,D)
    const float* key   = (const float*)d_in[1];   // (T,N,D)
    const float* value = (const float*)d_in[2];   // (T,N,D)
    const int*   lens  = (const int*)d_in[3];     // (N,)

    float* out = (float*)d_out;                   // first N*D floats
    float* att = out + N_DIM * D_DIM;             // next N*T floats

    float* blockmax = (float*)d_ws;                       // N*NCHUNK floats
    float* blocksum = (float*)((char*)d_ws + 8192);       // N*NCHUNK floats

    energy_kernel<<<N_DIM * NCHUNK, 256, 0, stream>>>(q, key, lens, att,
                                                      blockmax, blocksum);
    finalize_kernel<<<N_DIM, 256, 0, stream>>>(att, value,
                                               blockmax, blocksum, out);
}

// Round 2
// 457.363 us; speedup vs baseline: 1.0484x; 1.0297x over previous
//
#include <hip/hip_runtime.h>

#define T_DIM 4096
#define N_DIM 128
#define D_DIM 128
#define CHUNK 256
#define NCHUNK (T_DIM / CHUNK)   // 16
#define NDSZ   (N_DIM * D_DIM)   // 16384
#define NEGE (-1.0e9f)
#define P_SKIP 1.0e-9f           // skipped mass <= 4096*1e-9 ~ 4e-6 << tol

// ---------------------------------------------------------------------------
// K1: energy[n,t] = dot(key[t,n,:], q[n,:]).
// Layout: 8 lanes per t (each lane owns 16 d-elements as 4 float4 at
// 128-B-coalesced positions), so the cross-lane reduce is 3 shuffles, not 5.
// Loads are UNCONDITIONAL (t < T_DIM always; mask applied via select), so
// the inner loop is straight-line and fully pipelineable. Energies staged in
// LDS -> one coalesced float4 att store + clean block-reduce for chunk stats.
// Grid: N_DIM * NCHUNK blocks, 256 threads.
// ---------------------------------------------------------------------------
__global__ __launch_bounds__(256) void energy_kernel(
    const float* __restrict__ q,        // (N,D)
    const float* __restrict__ key,      // (T,N,D)
    const int*   __restrict__ lens,     // (N)
    float*       __restrict__ att,      // (N,T) raw energies
    float*       __restrict__ blockmax, // (N,NCHUNK)
    float*       __restrict__ blocksum) // (N,NCHUNK)
{
    const int b    = blockIdx.x;
    const int n    = b & (N_DIM - 1);
    const int c    = b >> 7;            // b / N_DIM
    const int t0   = c * CHUNK;
    const int len  = lens[n];
    const int tid  = threadIdx.x;

    // Fast path: whole chunk masked -> vector-write NEGE, no key reads.
    if (t0 >= len) {
        if (tid < 64)
            ((float4*)(att + (size_t)n * T_DIM + t0))[tid] =
                make_float4(NEGE, NEGE, NEGE, NEGE);
        if (tid == 0) {
            blockmax[n * NCHUNK + c] = NEGE;
            blocksum[n * NCHUNK + c] = 0.0f;
        }
        return;
    }

    __shared__ float sEv[CHUNK];
    __shared__ float sred[8];

    const int wave = tid >> 6;          // 0..3
    const int lane = tid & 63;
    const int dg   = lane & 7;          // d-group: lane's float4 column
    const int tg   = lane >> 3;         // t within the wave's 8-t group

    // q fragment: elements d = {dg*4 + k*32 + 0..3}, k=0..3 (permuted order,
    // sum-invariant). Each instruction is 128-B contiguous per 8-lane cluster.
    const float4* qp = (const float4*)(q + n * D_DIM) + dg;
    const float4 q0 = qp[0], q1 = qp[8], q2 = qp[16], q3 = qp[24];

    #pragma unroll
    for (int it = 0; it < 8; ++it) {
        const int t = t0 + wave * 64 + it * 8 + tg;
        const float4* kp = (const float4*)(key + (size_t)t * NDSZ + n * D_DIM) + dg;
        const float4 k0 = kp[0], k1 = kp[8], k2 = kp[16], k3 = kp[24];
        float p = k0.x * q0.x + k0.y * q0.y + k0.z * q0.z + k0.w * q0.w;
        p      += k1.x * q1.x + k1.y * q1.y + k1.z * q1.z + k1.w * q1.w;
        p      += k2.x * q2.x + k2.y * q2.y + k2.z * q2.z + k2.w * q2.w;
        p      += k3.x * q3.x + k3.y * q3.y + k3.z * q3.z + k3.w * q3.w;
        p += __shfl_xor(p, 1);
        p += __shfl_xor(p, 2);
        p += __shfl_xor(p, 4);
        const float e = (t < len) ? p : NEGE;   // no branch, no guarded load
        if (dg == 0) sEv[wave * 64 + it * 8 + tg] = e;   // 8 consecutive floats
    }
    __syncthreads();

    // Per-chunk stats: one energy per thread from LDS.
    const float e = sEv[tid];
    float m = e;
    m = fmaxf(m, __shfl_xor(m, 1));
    m = fmaxf(m, __shfl_xor(m, 2));
    m = fmaxf(m, __shfl_xor(m, 4));
    m = fmaxf(m, __shfl_xor(m, 8));
    m = fmaxf(m, __shfl_xor(m, 16));
    m = fmaxf(m, __shfl_xor(m, 32));
    if (lane == 0) sred[wave] = m;
    __syncthreads();
    m = fmaxf(fmaxf(sred[0], sred[1]), fmaxf(sred[2], sred[3]));

    float s = __expf(e - m);            // e==NEGE underflows to exact 0
    s += __shfl_xor(s, 1);
    s += __shfl_xor(s, 2);
    s += __shfl_xor(s, 4);
    s += __shfl_xor(s, 8);
    s += __shfl_xor(s, 16);
    s += __shfl_xor(s, 32);
    if (lane == 0) sred[4 + wave] = s;

    // Coalesced att store for the whole chunk (raw energies).
    if (tid < 64)
        ((float4*)(att + (size_t)n * T_DIM + t0))[tid] = ((const float4*)sEv)[tid];

    __syncthreads();
    if (tid == 0) {
        blockmax[n * NCHUNK + c] = m;
        blocksum[n * NCHUNK + c] = sred[4] + sred[5] + sred[6] + sred[7];
    }
}

// ---------------------------------------------------------------------------
// K2: per-n finalize. Rebuild global (m, Z); normalize full att row (raw ->
// p; masked tail -> exact 0 via exp underflow); ballot-aggregated compaction
// of {t : p > P_SKIP} (1 LDS atomic per wave per round, not per element);
// sparse PV over contributors; block-reduce; plain store.
// Grid: N_DIM blocks, 512 threads.
// ---------------------------------------------------------------------------
__global__ __launch_bounds__(512) void finalize_kernel(
    float*       __restrict__ att,      // (N,T): raw in, normalized out
    const float* __restrict__ value,    // (T,N,D)
    const float* __restrict__ blockmax, // (N,NCHUNK)
    const float* __restrict__ blocksum, // (N,NCHUNK)
    float*       __restrict__ out)      // (N,D)
{
    const int n   = blockIdx.x;
    const int tid = threadIdx.x;

    __shared__ float sm[NCHUNK], ss[NCHUNK];
    __shared__ float sp[T_DIM];         // 16 KB: normalized p for whole row
    __shared__ int   slist[T_DIM];      // 16 KB: contributor t-indices
    __shared__ int   scount;
    __shared__ float4 buf[512];

    if (tid < NCHUNK) {
        sm[tid] = blockmax[n * NCHUNK + tid];
        ss[tid] = blocksum[n * NCHUNK + tid];
    }
    if (tid == 0) scount = 0;
    __syncthreads();

    float m = sm[0];
    #pragma unroll
    for (int i = 1; i < NCHUNK; ++i) m = fmaxf(m, sm[i]);
    float Z = 0.f;
    #pragma unroll
    for (int i = 0; i < NCHUNK; ++i) Z += ss[i] * __expf(sm[i] - m);
    const float inv = 1.0f / Z;         // Z >= 1 (chunk holding global max)

    // Normalize full att row (float4), stash p in LDS. 2 passes @ 512 thr.
    float4* arow = (float4*)(att + (size_t)n * T_DIM);
    #pragma unroll
    for (int i = 0; i < T_DIM / 4 / 512; ++i) {
        const int idx = i * 512 + tid;
        float4 e4 = arow[idx];
        float4 p4;
        p4.x = __expf(e4.x - m) * inv;
        p4.y = __expf(e4.y - m) * inv;
        p4.z = __expf(e4.z - m) * inv;
        p4.w = __expf(e4.w - m) * inv;
        arow[idx] = p4;
        ((float4*)sp)[idx] = p4;
    }
    __syncthreads();

    // Ballot-aggregated compaction: one atomic per wave per round.
    const int lane = tid & 63;
    #pragma unroll
    for (int base = 0; base < T_DIM; base += 512) {
        const int t = base + tid;
        const bool pred = sp[t] > P_SKIP;   // masked tail is exact 0 -> excluded
        const unsigned long long mb = __ballot(pred);
        int wbase = 0;
        if (lane == 0) wbase = atomicAdd(&scount, __popcll(mb));
        wbase = __shfl(wbase, 0);
        if (pred) {
            const int prefix = __popcll(mb & ((1ULL << lane) - 1));
            slist[wbase + prefix] = t;
        }
    }
    __syncthreads();

    // Sparse PV: threads = (d-quad qd:32, list-group g:16); coalesced 512 B
    // value loads per 32-lane group.
    const int nc = scount;
    const int qd = tid & 31;
    const int g  = tid >> 5;
    float4 acc = make_float4(0.f, 0.f, 0.f, 0.f);
    for (int j = g; j < nc; j += 16) {
        const int t = slist[j];
        const float a = sp[t];
        const float4 v = *(const float4*)(value + (size_t)t * NDSZ
                                          + n * D_DIM + qd * 4);
        acc.x += a * v.x;
        acc.y += a * v.y;
        acc.z += a * v.z;
        acc.w += a * v.w;
    }

    buf[tid] = acc;
    __syncthreads();
    #pragma unroll
    for (int off = 256; off > 32; off >>= 1) {
        if (tid < off) {
            float4 o = buf[tid + off];
            buf[tid].x += o.x; buf[tid].y += o.y;
            buf[tid].z += o.z; buf[tid].w += o.w;
        }
        __syncthreads();
    }
    if (tid < 32) {
        float4 a0 = buf[tid];
        float4 a1 = buf[tid + 32];
        ((float4*)(out + n * D_DIM))[tid] =
            make_float4(a0.x + a1.x, a0.y + a1.y, a0.z + a1.z, a0.w + a1.w);
    }
}

extern "C" void kernel_launch(void* const* d_in, const int* in_sizes, int n_in,
                              void* d_out, int out_size, void* d_ws, size_t ws_size,
                              hipStream_t stream) {
    const float* q     = (const float*)d_in[0];   // (N,D)
    const float* key   = (const float*)d_in[1];   // (T,N,D)
    const float* value = (const float*)d_in[2];   // (T,N,D)
    const int*   lens  = (const int*)d_in[3];     // (N,)

    float* out = (float*)d_out;                   // first N*D floats
    float* att = out + N_DIM * D_DIM;             // next N*T floats

    float* blockmax = (float*)d_ws;                       // N*NCHUNK floats
    float* blocksum = (float*)((char*)d_ws + 8192);       // N*NCHUNK floats

    energy_kernel<<<N_DIM * NCHUNK, 256, 0, stream>>>(q, key, lens, att,
                                                      blockmax, blocksum);
    finalize_kernel<<<N_DIM, 512, 0, stream>>>(att, value,
                                               blockmax, blocksum, out);
}